// Round 7
// baseline (19973.619 us; speedup 1.0000x reference)
//
#include <hip/hip_runtime.h>
#include <hip/hip_bf16.h>
#include <cstddef>

typedef unsigned short u16;
typedef short bf16x8 __attribute__((ext_vector_type(8)));   // 8 bf16 bit-patterns (4 VGPRs)
typedef float f32x4 __attribute__((ext_vector_type(4)));
typedef unsigned short u16x8 __attribute__((ext_vector_type(8)));

#define MDIM 16384
#define NDIM 512

__device__ __forceinline__ float b2f(u16 u) {
    return __uint_as_float(((unsigned int)u) << 16);
}
__device__ __forceinline__ u16 f2b(float f) {  // round-to-nearest-even
    unsigned int x = __float_as_uint(f);
    x += 0x7fffu + ((x >> 16) & 1u);
    return (u16)(x >> 16);
}
__device__ __forceinline__ float tanh_fast(float x) {
    float a = fabsf(x);
    float e = __expf(-2.0f * a);
    float r = (1.0f - e) / (1.0f + e);
    return copysignf(r, x);
}

// ---------------- projection GEMM (verified R6 code, EPI0 only) -------------
template <int KDIM>
__global__ __launch_bounds__(256, 2) void gemm_proj(
    const float* __restrict__ Af, const u16* __restrict__ Bt,
    const float* __restrict__ bias, const float* __restrict__ addf,
    u16* __restrict__ Cb, float* __restrict__ Cf) {
    __shared__ u16 As[128 * 72];
    __shared__ u16 Bs[128 * 72];
    const int tid = threadIdx.x;
    const int m0 = blockIdx.y * 128;
    const int n0 = blockIdx.x * 128;
    const int lane = tid & 63;
    const int wave = tid >> 6;
    const int wm = (wave & 1) * 64;
    const int wn = (wave >> 1) * 64;
    const int lr = lane & 15;
    const int lk = (lane >> 4) * 8;

    f32x4 acc[4][4];
    f32x4 zero = {0.0f, 0.0f, 0.0f, 0.0f};
#pragma unroll
    for (int i = 0; i < 4; ++i)
#pragma unroll
        for (int j = 0; j < 4; ++j) acc[i][j] = zero;

    const int r0 = tid >> 3;
    const int c0 = (tid & 7) * 8;

    for (int kt = 0; kt < KDIM / 64; ++kt) {
        const int k0 = kt * 64;
#pragma unroll
        for (int it = 0; it < 4; ++it) {
            int r = it * 32 + r0;
            const float* src = Af + (size_t)(m0 + r) * KDIM + k0 + c0;
            f32x4 lo = *(const f32x4*)(src);
            f32x4 hi = *(const f32x4*)(src + 4);
            u16x8 t;
#pragma unroll
            for (int q = 0; q < 4; ++q) { t[q] = f2b(lo[q]); t[q + 4] = f2b(hi[q]); }
            *(u16x8*)(&As[r * 72 + c0]) = t;
            *(f32x4*)(&Bs[r * 72 + c0]) =
                *(const f32x4*)(Bt + (size_t)(n0 + r) * KDIM + k0 + c0);
        }
        __syncthreads();
#pragma unroll
        for (int kk = 0; kk < 2; ++kk) {
            bf16x8 af[4], bw[4];
#pragma unroll
            for (int i = 0; i < 4; ++i) {
                af[i] = __builtin_bit_cast(
                    bf16x8, *(const f32x4*)(&As[(wm + i * 16 + lr) * 72 + kk * 32 + lk]));
                bw[i] = __builtin_bit_cast(
                    bf16x8, *(const f32x4*)(&Bs[(wn + i * 16 + lr) * 72 + kk * 32 + lk]));
            }
#pragma unroll
            for (int i = 0; i < 4; ++i)
#pragma unroll
                for (int j = 0; j < 4; ++j)
                    acc[i][j] = __builtin_amdgcn_mfma_f32_16x16x32_bf16(
                        af[i], bw[j], acc[i][j], 0, 0, 0);
        }
        __syncthreads();
    }
#pragma unroll
    for (int j = 0; j < 4; ++j) {
        const int col = n0 + wn + j * 16 + lr;
        const float bv = bias[col];
#pragma unroll
        for (int i = 0; i < 4; ++i) {
            const int rowb = m0 + wm + i * 16 + (lane >> 4) * 4;
#pragma unroll
            for (int r = 0; r < 4; ++r) {
                float v = acc[i][j][r] + bv;
                size_t off = (size_t)(rowb + r) * NDIM + col;
                v += addf[off];
                Cf[off] = v;
                Cb[off] = f2b(v);
            }
        }
    }
}

// ---------------- fused 3-layer MLP + dopri5 stage combo --------------------
// Block: 64 rows x 512 cols. 4 waves in 2x2: wave = 32 rows x 256 cols
// (2 row-tiles x 16 col-tiles of 16x16x32 MFMA; acc 128 VGPR per array).
// h1/h2 stay in accumulators; C/D -> A-frag transform via 64x128 LDS scratch
// chunks. Weights stream L2 -> LDS per 32-k tile.
// Epilogue: kv = acc + b3 -> kout (bf16); combo = S32 + sum(cs*kprev) + cown*kv
// -> comboB (bf16) and optionally comboF (fp32).
__global__ __launch_bounds__(256, 1) void fused_mlp(
    const u16* __restrict__ in,
    const u16* __restrict__ W1t, const u16* __restrict__ W2t,
    const u16* __restrict__ W3t,
    const float* __restrict__ b1, const float* __restrict__ b2,
    const float* __restrict__ b3,
    u16* __restrict__ kout, const float* __restrict__ S32,
    const u16* __restrict__ kp1, const u16* __restrict__ kp2,
    const u16* __restrict__ kp3, const u16* __restrict__ kp4,
    float c1, float c2, float c3, float c4, float cown, int nprev,
    float* __restrict__ comboF, u16* __restrict__ comboB) {
    __shared__ u16 Wt[512 * 40];   // [n][32k], stride 40 u16 (16B-aligned rows)
    __shared__ u16 hs[64 * 136];   // h chunk: 64 rows x 128 k, stride 136

    const int tid = threadIdx.x;
    const int lane = tid & 63, wave = tid >> 6;
    const int wr = wave >> 1, wc = wave & 1;
    const int lr = lane & 15, lq = lane >> 4;
    const int row0 = blockIdx.x * 64;
    const f32x4 zero = {0.0f, 0.0f, 0.0f, 0.0f};

    f32x4 accA[2][16], accB[2][16];

    // stage the [512 n][32 k] tile of W for kstep ks into Wt
    auto stageW = [&](const u16* W, int ks) {
        const u16* src = W + (size_t)(2 * tid) * 512 + ks * 32;
#pragma unroll
        for (int e = 0; e < 2; ++e) {
            f32x4 v0 = *(const f32x4*)(src);
            f32x4 v1 = *(const f32x4*)(src + 8);
            f32x4 v2 = *(const f32x4*)(src + 16);
            f32x4 v3 = *(const f32x4*)(src + 24);
            u16* dst = &Wt[(2 * tid + e) * 40];
            *(f32x4*)(dst) = v0;
            *(f32x4*)(dst + 8) = v1;
            *(f32x4*)(dst + 16) = v2;
            *(f32x4*)(dst + 24) = v3;
            src += 512;
        }
    };

    // ---- layer 1: A from global 'in' ----
#pragma unroll
    for (int rt = 0; rt < 2; ++rt)
#pragma unroll
        for (int jt = 0; jt < 16; ++jt) accA[rt][jt] = zero;

    for (int ks = 0; ks < 16; ++ks) {
        __syncthreads();
        stageW(W1t, ks);
        __syncthreads();
        bf16x8 a0 = __builtin_bit_cast(bf16x8,
            *(const f32x4*)(in + (size_t)(row0 + wr * 32 + lr) * 512 + ks * 32 + lq * 8));
        bf16x8 a1 = __builtin_bit_cast(bf16x8,
            *(const f32x4*)(in + (size_t)(row0 + wr * 32 + 16 + lr) * 512 + ks * 32 + lq * 8));
#pragma unroll
        for (int jt = 0; jt < 16; ++jt) {
            bf16x8 b = __builtin_bit_cast(bf16x8,
                *(const f32x4*)(&Wt[(wc * 256 + 16 * jt + lr) * 40 + lq * 8]));
            accA[0][jt] = __builtin_amdgcn_mfma_f32_16x16x32_bf16(a0, b, accA[0][jt], 0, 0, 0);
            accA[1][jt] = __builtin_amdgcn_mfma_f32_16x16x32_bf16(a1, b, accA[1][jt], 0, 0, 0);
        }
    }

    // ---- layers 2 & 3: A = tanh(srcAcc + biasPrev) via hs chunks ----
    auto layer_hs = [&](const u16* W, const float* biasPrev,
                        f32x4 (&srcAcc)[2][16], f32x4 (&dstAcc)[2][16]) {
#pragma unroll
        for (int rt = 0; rt < 2; ++rt)
#pragma unroll
            for (int jt = 0; jt < 16; ++jt) dstAcc[rt][jt] = zero;

        for (int c = 0; c < 4; ++c) {
            __syncthreads();   // prior chunk fully consumed
            if (wc == (c >> 1)) {
#pragma unroll
                for (int jl = 0; jl < 8; ++jl) {
                    int jt = 8 * (c & 1) + jl;
                    int colg = wc * 256 + 16 * jt + lr;
                    float bv = biasPrev[colg];
#pragma unroll
                    for (int rt = 0; rt < 2; ++rt)
#pragma unroll
                        for (int r = 0; r < 4; ++r) {
                            int rowl = wr * 32 + 16 * rt + lq * 4 + r;
                            hs[rowl * 136 + 16 * jl + lr] =
                                f2b(tanh_fast(srcAcc[rt][jt][r] + bv));
                        }
                }
            }
            __syncthreads();   // chunk visible to all waves
            for (int kt = 0; kt < 4; ++kt) {
                int ks = 4 * c + kt;
                __syncthreads();
                stageW(W, ks);
                __syncthreads();
                bf16x8 a0 = __builtin_bit_cast(bf16x8,
                    *(const f32x4*)(&hs[(wr * 32 + lr) * 136 + kt * 32 + lq * 8]));
                bf16x8 a1 = __builtin_bit_cast(bf16x8,
                    *(const f32x4*)(&hs[(wr * 32 + 16 + lr) * 136 + kt * 32 + lq * 8]));
#pragma unroll
                for (int jt = 0; jt < 16; ++jt) {
                    bf16x8 b = __builtin_bit_cast(bf16x8,
                        *(const f32x4*)(&Wt[(wc * 256 + 16 * jt + lr) * 40 + lq * 8]));
                    dstAcc[0][jt] =
                        __builtin_amdgcn_mfma_f32_16x16x32_bf16(a0, b, dstAcc[0][jt], 0, 0, 0);
                    dstAcc[1][jt] =
                        __builtin_amdgcn_mfma_f32_16x16x32_bf16(a1, b, dstAcc[1][jt], 0, 0, 0);
                }
            }
        }
    };

    layer_hs(W2t, b1, accA, accB);
    layer_hs(W3t, b2, accB, accA);

    // ---- epilogue: k output + fused stage combo ----
    const u16* kps[4] = {kp1, kp2, kp3, kp4};
    float cs[4] = {c1, c2, c3, c4};
#pragma unroll
    for (int jt = 0; jt < 16; ++jt) {
        int colg = wc * 256 + 16 * jt + lr;
        float bv = b3[colg];
#pragma unroll
        for (int rt = 0; rt < 2; ++rt)
#pragma unroll
            for (int r = 0; r < 4; ++r) {
                int rowg = row0 + wr * 32 + 16 * rt + lq * 4 + r;
                size_t off = (size_t)rowg * 512 + colg;
                float kv = accA[rt][jt][r] + bv;
                kout[off] = f2b(kv);
                float cb = S32[off] + cown * kv;
                for (int t = 0; t < nprev; ++t) cb += cs[t] * b2f(kps[t][off]);
                comboB[off] = f2b(cb);
                if (comboF) comboF[off] = cb;
            }
    }
}

// out_bf16[c*R + r] = in_f32[r*Ncols + c]   (weight transpose + cast, tiny)
__global__ void transpose_k(const float* __restrict__ in, u16* __restrict__ out,
                            int R, int Ncols) {
    int idx = blockIdx.x * 256 + threadIdx.x;
    int r = idx / Ncols, c = idx % Ncols;
    out[(size_t)c * R + r] = f2b(in[idx]);
}

extern "C" void kernel_launch(void* const* d_in, const int* in_sizes, int n_in,
                              void* d_out, int out_size, void* d_ws, size_t ws_size,
                              hipStream_t stream) {
    // ---- order-robust input mapping via in_sizes ----
    const float *y = nullptr, *u_t = nullptr, *Wp = nullptr, *bp = nullptr;
    const float *W1 = nullptr, *b1 = nullptr, *W2 = nullptr, *b2 = nullptr;
    const float *W3 = nullptr, *b3 = nullptr;
    {
        const float* w262[3] = {nullptr, nullptr, nullptr};
        const float* s512[4] = {nullptr, nullptr, nullptr, nullptr};
        int i512[4] = {0, 0, 0, 0};
        int n262 = 0, n512 = 0;
        for (int i = 0; i < n_in; ++i) {
            const float* p = (const float*)d_in[i];
            int sz = in_sizes[i];
            if (sz == MDIM * NDIM) y = p;
            else if (sz == MDIM * 256) u_t = p;
            else if (sz == 256 * 512) Wp = p;
            else if (sz == 512 * 512) { if (n262 < 3) w262[n262++] = p; }
            else if (sz == 512) { if (n512 < 4) { i512[n512] = i; s512[n512++] = p; } }
        }
        W1 = w262[0]; W2 = w262[1]; W3 = w262[2];
        bool contig = (n512 == 4) && (i512[3] == i512[0] + 3);
        if (contig) { b1 = s512[0]; b2 = s512[1]; b3 = s512[2]; bp = s512[3]; }
        else        { bp = s512[0]; b1 = s512[1]; b2 = s512[2]; b3 = s512[3]; }
        if (!y || !u_t || !Wp || !W1 || n512 < 4) {
            y  = (const float*)d_in[0]; u_t = (const float*)d_in[1];
            Wp = (const float*)d_in[2]; bp  = (const float*)d_in[3];
            W1 = (const float*)d_in[4]; b1  = (const float*)d_in[5];
            W2 = (const float*)d_in[6]; b2  = (const float*)d_in[7];
            W3 = (const float*)d_in[8]; b3  = (const float*)d_in[9];
        }
    }

    u16* ws  = (u16*)d_ws;
    u16* Wpt = ws;                    // 512x256 bf16  (N x K, K contiguous)
    u16* W1t = Wpt + 512 * 256;       // 512x512 bf16
    u16* W2t = W1t + 512 * 512;
    u16* W3t = W2t + 512 * 512;
    const size_t wfix = 512 * 256 + 3 * 512 * 512;

    // adaptive chunking: per row 9*512 u16 (S32:2, Sb:1, T0b:1, K1..K5:5)
    long wsElems = (long)(ws_size / 2);
    long chunk = (wsElems - (long)wfix) / (9L * NDIM);
    chunk = (chunk / 128) * 128;
    if (chunk > MDIM) chunk = MDIM;
    if (chunk < 128) chunk = 128;

    transpose_k<<<512, 256, 0, stream>>>(Wp, Wpt, 256, 512);
    transpose_k<<<1024, 256, 0, stream>>>(W1, W1t, 512, 512);
    transpose_k<<<1024, 256, 0, stream>>>(W2, W2t, 512, 512);
    transpose_k<<<1024, 256, 0, stream>>>(W3, W3t, 512, 512);

    const double h = 0.1 / 8.0;
    float* OUT = (float*)d_out;

    for (long row0 = 0; row0 < MDIM; row0 += chunk) {
        const long rows = (MDIM - row0 < chunk) ? (MDIM - row0) : chunk;
        const size_t CB = (size_t)rows * NDIM;

        u16* base = ws + wfix;
        float* S32 = (float*)base;          // 2*CB u16
        u16* Sb  = base + 2 * CB;
        u16* T0b = base + 3 * CB;
        u16* K1  = base + 4 * CB;
        u16* K2  = base + 5 * CB;
        u16* K3  = base + 6 * CB;
        u16* K4  = base + 7 * CB;
        u16* K5  = base + 8 * CB;
        u16* K6  = K2;                      // k2 dead by stage 6; reuse

        dim3 gg(4, (unsigned)(rows / 128));
        const unsigned gf = (unsigned)(rows / 64);

        // S = u_t @ Wp + bp + y  -> S32 (fp32) + Sb (bf16)
        gemm_proj<256><<<gg, 256, 0, stream>>>(
            u_t + (size_t)row0 * 256, Wpt, bp, y + (size_t)row0 * NDIM, Sb, S32);

        for (int st = 0; st < 8; ++st) {
            // eval 1: k1; combo -> T0b = S + (h/5) k1
            fused_mlp<<<gf, 256, 0, stream>>>(
                Sb, W1t, W2t, W3t, b1, b2, b3, K1, S32,
                nullptr, nullptr, nullptr, nullptr,
                0.f, 0.f, 0.f, 0.f, (float)(h / 5.0), 0, nullptr, T0b);
            // eval 2: k2; combo = S + 3h/40 k1 + 9h/40 k2
            fused_mlp<<<gf, 256, 0, stream>>>(
                T0b, W1t, W2t, W3t, b1, b2, b3, K2, S32,
                K1, nullptr, nullptr, nullptr,
                (float)(h * 3.0 / 40.0), 0.f, 0.f, 0.f,
                (float)(h * 9.0 / 40.0), 1, nullptr, T0b);
            // eval 3
            fused_mlp<<<gf, 256, 0, stream>>>(
                T0b, W1t, W2t, W3t, b1, b2, b3, K3, S32,
                K1, K2, nullptr, nullptr,
                (float)(h * 44.0 / 45.0), (float)(h * -56.0 / 15.0), 0.f, 0.f,
                (float)(h * 32.0 / 9.0), 2, nullptr, T0b);
            // eval 4
            fused_mlp<<<gf, 256, 0, stream>>>(
                T0b, W1t, W2t, W3t, b1, b2, b3, K4, S32,
                K1, K2, K3, nullptr,
                (float)(h * 19372.0 / 6561.0), (float)(h * -25360.0 / 2187.0),
                (float)(h * 64448.0 / 6561.0), 0.f,
                (float)(h * -212.0 / 729.0), 3, nullptr, T0b);
            // eval 5
            fused_mlp<<<gf, 256, 0, stream>>>(
                T0b, W1t, W2t, W3t, b1, b2, b3, K5, S32,
                K1, K2, K3, K4,
                (float)(h * 9017.0 / 3168.0), (float)(h * -355.0 / 33.0),
                (float)(h * 46732.0 / 5247.0), (float)(h * 49.0 / 176.0),
                (float)(h * -5103.0 / 18656.0), 4, nullptr, T0b);
            // eval 6: k6; combo = y-update (B row) -> S32 (or OUT) + Sb
            float* dstF = (st == 7) ? (OUT + (size_t)row0 * NDIM) : S32;
            fused_mlp<<<gf, 256, 0, stream>>>(
                T0b, W1t, W2t, W3t, b1, b2, b3, K6, S32,
                K1, K3, K4, K5,
                (float)(h * 35.0 / 384.0), (float)(h * 500.0 / 1113.0),
                (float)(h * 125.0 / 192.0), (float)(h * -2187.0 / 6784.0),
                (float)(h * 11.0 / 84.0), 4, dstF, Sb);
        }
    }
}

// Round 8
// 8869.476 us; speedup vs baseline: 2.2520x; 2.2520x over previous
//
#include <hip/hip_runtime.h>
#include <hip/hip_bf16.h>
#include <cstddef>

typedef unsigned short u16;
typedef short bf16x8 __attribute__((ext_vector_type(8)));   // 8 bf16 bit-patterns (4 VGPRs)
typedef float f32x4 __attribute__((ext_vector_type(4)));
typedef unsigned short u16x8 __attribute__((ext_vector_type(8)));

#define MDIM 16384
#define NDIM 512

__device__ __forceinline__ float b2f(u16 u) {
    return __uint_as_float(((unsigned int)u) << 16);
}
__device__ __forceinline__ u16 f2b(float f) {  // round-to-nearest-even
    unsigned int x = __float_as_uint(f);
    x += 0x7fffu + ((x >> 16) & 1u);
    return (u16)(x >> 16);
}
__device__ __forceinline__ float tanh_fast(float x) {
    float a = fabsf(x);
    float e = __expf(-2.0f * a);
    float r = (1.0f - e) / (1.0f + e);
    return copysignf(r, x);
}

// ---------------- projection GEMM (verified, EPI0 only) ---------------------
template <int KDIM>
__global__ __launch_bounds__(256, 2) void gemm_proj(
    const float* __restrict__ Af, const u16* __restrict__ Bt,
    const float* __restrict__ bias, const float* __restrict__ addf,
    u16* __restrict__ Cb, float* __restrict__ Cf) {
    __shared__ u16 As[128 * 72];
    __shared__ u16 Bs[128 * 72];
    const int tid = threadIdx.x;
    const int m0 = blockIdx.y * 128;
    const int n0 = blockIdx.x * 128;
    const int lane = tid & 63;
    const int wave = tid >> 6;
    const int wm = (wave & 1) * 64;
    const int wn = (wave >> 1) * 64;
    const int lr = lane & 15;
    const int lk = (lane >> 4) * 8;

    f32x4 acc[4][4];
    f32x4 zero = {0.0f, 0.0f, 0.0f, 0.0f};
#pragma unroll
    for (int i = 0; i < 4; ++i)
#pragma unroll
        for (int j = 0; j < 4; ++j) acc[i][j] = zero;

    const int r0 = tid >> 3;
    const int c0 = (tid & 7) * 8;

    for (int kt = 0; kt < KDIM / 64; ++kt) {
        const int k0 = kt * 64;
#pragma unroll
        for (int it = 0; it < 4; ++it) {
            int r = it * 32 + r0;
            const float* src = Af + (size_t)(m0 + r) * KDIM + k0 + c0;
            f32x4 lo = *(const f32x4*)(src);
            f32x4 hi = *(const f32x4*)(src + 4);
            u16x8 t;
#pragma unroll
            for (int q = 0; q < 4; ++q) { t[q] = f2b(lo[q]); t[q + 4] = f2b(hi[q]); }
            *(u16x8*)(&As[r * 72 + c0]) = t;
            *(f32x4*)(&Bs[r * 72 + c0]) =
                *(const f32x4*)(Bt + (size_t)(n0 + r) * KDIM + k0 + c0);
        }
        __syncthreads();
#pragma unroll
        for (int kk = 0; kk < 2; ++kk) {
            bf16x8 af[4], bw[4];
#pragma unroll
            for (int i = 0; i < 4; ++i) {
                af[i] = __builtin_bit_cast(
                    bf16x8, *(const f32x4*)(&As[(wm + i * 16 + lr) * 72 + kk * 32 + lk]));
                bw[i] = __builtin_bit_cast(
                    bf16x8, *(const f32x4*)(&Bs[(wn + i * 16 + lr) * 72 + kk * 32 + lk]));
            }
#pragma unroll
            for (int i = 0; i < 4; ++i)
#pragma unroll
                for (int j = 0; j < 4; ++j)
                    acc[i][j] = __builtin_amdgcn_mfma_f32_16x16x32_bf16(
                        af[i], bw[j], acc[i][j], 0, 0, 0);
        }
        __syncthreads();
    }
#pragma unroll
    for (int j = 0; j < 4; ++j) {
        const int col = n0 + wn + j * 16 + lr;
        const float bv = bias[col];
#pragma unroll
        for (int i = 0; i < 4; ++i) {
            const int rowb = m0 + wm + i * 16 + (lane >> 4) * 4;
#pragma unroll
            for (int r = 0; r < 4; ++r) {
                float v = acc[i][j][r] + bv;
                size_t off = (size_t)(rowb + r) * NDIM + col;
                v += addf[off];
                Cf[off] = v;
                Cb[off] = f2b(v);
            }
        }
    }
}

// ---------------- fused 3-layer MLP + dopri5 stage combo --------------------
// Block: 32 rows x 512 cols, 4 waves (wave=wc owns 128 cols, all 32 rows).
// acc[2][8] = 64 VGPRs only array live. h round-trips through full-width LDS
// (32 x 520 u16 = 33 KB). B-frags read straight from L2-resident weights.
__global__ __launch_bounds__(256, 2) void fused_mlp(
    const u16* __restrict__ in,
    const u16* __restrict__ W1t, const u16* __restrict__ W2t,
    const u16* __restrict__ W3t,
    const float* __restrict__ b1, const float* __restrict__ b2,
    const float* __restrict__ b3,
    u16* __restrict__ kout, const float* __restrict__ S32,
    const u16* __restrict__ kp1, const u16* __restrict__ kp2,
    const u16* __restrict__ kp3, const u16* __restrict__ kp4,
    float c1, float c2, float c3, float c4, float cown, int nprev,
    float* __restrict__ comboF, u16* __restrict__ comboB) {
    __shared__ u16 hs[32 * 520];   // [row][col], stride 520 breaks conflicts

    const int tid = threadIdx.x;
    const int lane = tid & 63, wave = tid >> 6;   // wave = column quarter
    const int lr = lane & 15, lq = lane >> 4;
    const int row0 = blockIdx.x * 32;
    const f32x4 zero = {0.0f, 0.0f, 0.0f, 0.0f};

    // stage 'in' (bf16) rows into hs, coalesced: thread -> 64 contiguous u16
    {
        const int r = tid >> 3;
        const int c = (tid & 7) * 64;
        const u16* src = in + (size_t)(row0 + r) * 512 + c;
        u16* dst = &hs[r * 520 + c];
#pragma unroll
        for (int q = 0; q < 8; ++q)
            *(f32x4*)(dst + q * 8) = *(const f32x4*)(src + q * 8);
    }

    f32x4 acc[2][8];

    auto run_layer = [&](const u16* __restrict__ W) {
#pragma unroll
        for (int rt = 0; rt < 2; ++rt)
#pragma unroll
            for (int jt = 0; jt < 8; ++jt) acc[rt][jt] = zero;
        for (int ks = 0; ks < 16; ++ks) {
            bf16x8 a0 = __builtin_bit_cast(
                bf16x8, *(const f32x4*)(&hs[lr * 520 + ks * 32 + lq * 8]));
            bf16x8 a1 = __builtin_bit_cast(
                bf16x8, *(const f32x4*)(&hs[(16 + lr) * 520 + ks * 32 + lq * 8]));
#pragma unroll
            for (int jt = 0; jt < 8; ++jt) {
                const u16* wp =
                    W + (size_t)(wave * 128 + 16 * jt + lr) * 512 + ks * 32 + lq * 8;
                bf16x8 b = __builtin_bit_cast(bf16x8, *(const f32x4*)wp);
                acc[0][jt] = __builtin_amdgcn_mfma_f32_16x16x32_bf16(a0, b, acc[0][jt], 0, 0, 0);
                acc[1][jt] = __builtin_amdgcn_mfma_f32_16x16x32_bf16(a1, b, acc[1][jt], 0, 0, 0);
            }
        }
    };

    auto write_h = [&](const float* __restrict__ bias) {
        __syncthreads();   // all waves done reading hs (previous layer)
#pragma unroll
        for (int jt = 0; jt < 8; ++jt) {
            const int colg = wave * 128 + 16 * jt + lr;
            const float bv = bias[colg];
#pragma unroll
            for (int rt = 0; rt < 2; ++rt)
#pragma unroll
                for (int r = 0; r < 4; ++r) {
                    const int rowl = 16 * rt + lq * 4 + r;
                    hs[rowl * 520 + colg] = f2b(tanh_fast(acc[rt][jt][r] + bv));
                }
        }
        __syncthreads();   // hs complete for next layer
    };

    __syncthreads();       // 'in' staged
    run_layer(W1t);
    write_h(b1);
    run_layer(W2t);
    write_h(b2);
    run_layer(W3t);

    // epilogue: kv -> kout (bf16); combo = S32 + sum(ci*kpi) + cown*kv
#pragma unroll
    for (int jt = 0; jt < 8; ++jt) {
        const int colg = wave * 128 + 16 * jt + lr;
        const float bv = b3[colg];
#pragma unroll
        for (int rt = 0; rt < 2; ++rt)
#pragma unroll
            for (int r = 0; r < 4; ++r) {
                const int rowg = row0 + 16 * rt + lq * 4 + r;
                const size_t off = (size_t)rowg * 512 + colg;
                float kv = acc[rt][jt][r] + bv;
                kout[off] = f2b(kv);
                float cb = S32[off] + cown * kv;
                if (nprev > 0) cb += c1 * b2f(kp1[off]);
                if (nprev > 1) cb += c2 * b2f(kp2[off]);
                if (nprev > 2) cb += c3 * b2f(kp3[off]);
                if (nprev > 3) cb += c4 * b2f(kp4[off]);
                comboB[off] = f2b(cb);
                if (comboF) comboF[off] = cb;
            }
    }
}

// out_bf16[c*R + r] = in_f32[r*Ncols + c]   (weight transpose + cast, tiny)
__global__ void transpose_k(const float* __restrict__ in, u16* __restrict__ out,
                            int R, int Ncols) {
    int idx = blockIdx.x * 256 + threadIdx.x;
    int r = idx / Ncols, c = idx % Ncols;
    out[(size_t)c * R + r] = f2b(in[idx]);
}

extern "C" void kernel_launch(void* const* d_in, const int* in_sizes, int n_in,
                              void* d_out, int out_size, void* d_ws, size_t ws_size,
                              hipStream_t stream) {
    // ---- order-robust input mapping via in_sizes ----
    const float *y = nullptr, *u_t = nullptr, *Wp = nullptr, *bp = nullptr;
    const float *W1 = nullptr, *b1 = nullptr, *W2 = nullptr, *b2 = nullptr;
    const float *W3 = nullptr, *b3 = nullptr;
    {
        const float* w262[3] = {nullptr, nullptr, nullptr};
        const float* s512[4] = {nullptr, nullptr, nullptr, nullptr};
        int i512[4] = {0, 0, 0, 0};
        int n262 = 0, n512 = 0;
        for (int i = 0; i < n_in; ++i) {
            const float* p = (const float*)d_in[i];
            int sz = in_sizes[i];
            if (sz == MDIM * NDIM) y = p;
            else if (sz == MDIM * 256) u_t = p;
            else if (sz == 256 * 512) Wp = p;
            else if (sz == 512 * 512) { if (n262 < 3) w262[n262++] = p; }
            else if (sz == 512) { if (n512 < 4) { i512[n512] = i; s512[n512++] = p; } }
        }
        W1 = w262[0]; W2 = w262[1]; W3 = w262[2];
        bool contig = (n512 == 4) && (i512[3] == i512[0] + 3);
        if (contig) { b1 = s512[0]; b2 = s512[1]; b3 = s512[2]; bp = s512[3]; }
        else        { bp = s512[0]; b1 = s512[1]; b2 = s512[2]; b3 = s512[3]; }
        if (!y || !u_t || !Wp || !W1 || n512 < 4) {
            y  = (const float*)d_in[0]; u_t = (const float*)d_in[1];
            Wp = (const float*)d_in[2]; bp  = (const float*)d_in[3];
            W1 = (const float*)d_in[4]; b1  = (const float*)d_in[5];
            W2 = (const float*)d_in[6]; b2  = (const float*)d_in[7];
            W3 = (const float*)d_in[8]; b3  = (const float*)d_in[9];
        }
    }

    u16* ws  = (u16*)d_ws;
    u16* Wpt = ws;                    // 512x256 bf16  (N x K, K contiguous)
    u16* W1t = Wpt + 512 * 256;       // 512x512 bf16
    u16* W2t = W1t + 512 * 512;
    u16* W3t = W2t + 512 * 512;
    const size_t wfix = 512 * 256 + 3 * 512 * 512;

    // adaptive chunking: per row 9*512 u16 (S32:2, Sb:1, T0b:1, K1..K5:5)
    long wsElems = (long)(ws_size / 2);
    long chunk = (wsElems - (long)wfix) / (9L * NDIM);
    chunk = (chunk / 128) * 128;
    if (chunk > MDIM) chunk = MDIM;
    if (chunk < 128) chunk = 128;

    transpose_k<<<512, 256, 0, stream>>>(Wp, Wpt, 256, 512);
    transpose_k<<<1024, 256, 0, stream>>>(W1, W1t, 512, 512);
    transpose_k<<<1024, 256, 0, stream>>>(W2, W2t, 512, 512);
    transpose_k<<<1024, 256, 0, stream>>>(W3, W3t, 512, 512);

    const double h = 0.1 / 8.0;
    float* OUT = (float*)d_out;

    for (long row0 = 0; row0 < MDIM; row0 += chunk) {
        const long rows = (MDIM - row0 < chunk) ? (MDIM - row0) : chunk;
        const size_t CB = (size_t)rows * NDIM;

        u16* base = ws + wfix;
        float* S32 = (float*)base;          // 2*CB u16
        u16* Sb  = base + 2 * CB;
        u16* T0b = base + 3 * CB;
        u16* K1  = base + 4 * CB;
        u16* K2  = base + 5 * CB;
        u16* K3  = base + 6 * CB;
        u16* K4  = base + 7 * CB;
        u16* K5  = base + 8 * CB;
        u16* K6  = K2;                      // k2 dead by stage 6; reuse

        dim3 gg(4, (unsigned)(rows / 128));
        const unsigned gf = (unsigned)(rows / 32);

        // S = u_t @ Wp + bp + y  -> S32 (fp32) + Sb (bf16)
        gemm_proj<256><<<gg, 256, 0, stream>>>(
            u_t + (size_t)row0 * 256, Wpt, bp, y + (size_t)row0 * NDIM, Sb, S32);

        for (int st = 0; st < 8; ++st) {
            fused_mlp<<<gf, 256, 0, stream>>>(
                Sb, W1t, W2t, W3t, b1, b2, b3, K1, S32,
                nullptr, nullptr, nullptr, nullptr,
                0.f, 0.f, 0.f, 0.f, (float)(h / 5.0), 0, nullptr, T0b);
            fused_mlp<<<gf, 256, 0, stream>>>(
                T0b, W1t, W2t, W3t, b1, b2, b3, K2, S32,
                K1, nullptr, nullptr, nullptr,
                (float)(h * 3.0 / 40.0), 0.f, 0.f, 0.f,
                (float)(h * 9.0 / 40.0), 1, nullptr, T0b);
            fused_mlp<<<gf, 256, 0, stream>>>(
                T0b, W1t, W2t, W3t, b1, b2, b3, K3, S32,
                K1, K2, nullptr, nullptr,
                (float)(h * 44.0 / 45.0), (float)(h * -56.0 / 15.0), 0.f, 0.f,
                (float)(h * 32.0 / 9.0), 2, nullptr, T0b);
            fused_mlp<<<gf, 256, 0, stream>>>(
                T0b, W1t, W2t, W3t, b1, b2, b3, K4, S32,
                K1, K2, K3, nullptr,
                (float)(h * 19372.0 / 6561.0), (float)(h * -25360.0 / 2187.0),
                (float)(h * 64448.0 / 6561.0), 0.f,
                (float)(h * -212.0 / 729.0), 3, nullptr, T0b);
            fused_mlp<<<gf, 256, 0, stream>>>(
                T0b, W1t, W2t, W3t, b1, b2, b3, K5, S32,
                K1, K2, K3, K4,
                (float)(h * 9017.0 / 3168.0), (float)(h * -355.0 / 33.0),
                (float)(h * 46732.0 / 5247.0), (float)(h * 49.0 / 176.0),
                (float)(h * -5103.0 / 18656.0), 4, nullptr, T0b);
            float* dstF = (st == 7) ? (OUT + (size_t)row0 * NDIM) : S32;
            fused_mlp<<<gf, 256, 0, stream>>>(
                T0b, W1t, W2t, W3t, b1, b2, b3, K6, S32,
                K1, K3, K4, K5,
                (float)(h * 35.0 / 384.0), (float)(h * 500.0 / 1113.0),
                (float)(h * 125.0 / 192.0), (float)(h * -2187.0 / 6784.0),
                (float)(h * 11.0 / 84.0), 4, dstF, Sb);
        }
    }
}